// Round 3
// baseline (1308.077 us; speedup 1.0000x reference)
//
#include <hip/hip_runtime.h>
#include <stdint.h>
#include <stddef.h>

#define N_NODES 100000
#define N_EDGES 6400000
#define HIDDEN 16

__host__ __device__ inline uint32_t rotl32(uint32_t x, int n) {
    return (x << n) | (x >> (32 - n));
}

// Exact JAX threefry2x32 (20 rounds)
__host__ __device__ inline void threefry2x32(uint32_t k0, uint32_t k1,
                                             uint32_t x0, uint32_t x1,
                                             uint32_t& o0, uint32_t& o1) {
    uint32_t k2 = k0 ^ k1 ^ 0x1BD11BDAu;
    x0 += k0; x1 += k1;
    x0 += x1; x1 = rotl32(x1, 13); x1 ^= x0;
    x0 += x1; x1 = rotl32(x1, 15); x1 ^= x0;
    x0 += x1; x1 = rotl32(x1, 26); x1 ^= x0;
    x0 += x1; x1 = rotl32(x1,  6); x1 ^= x0;
    x0 += k1; x1 += k2 + 1u;
    x0 += x1; x1 = rotl32(x1, 17); x1 ^= x0;
    x0 += x1; x1 = rotl32(x1, 29); x1 ^= x0;
    x0 += x1; x1 = rotl32(x1, 16); x1 ^= x0;
    x0 += x1; x1 = rotl32(x1, 24); x1 ^= x0;
    x0 += k2; x1 += k0 + 2u;
    x0 += x1; x1 = rotl32(x1, 13); x1 ^= x0;
    x0 += x1; x1 = rotl32(x1, 15); x1 ^= x0;
    x0 += x1; x1 = rotl32(x1, 26); x1 ^= x0;
    x0 += x1; x1 = rotl32(x1,  6); x1 ^= x0;
    x0 += k0; x1 += k1 + 3u;
    x0 += x1; x1 = rotl32(x1, 17); x1 ^= x0;
    x0 += x1; x1 = rotl32(x1, 29); x1 ^= x0;
    x0 += x1; x1 = rotl32(x1, 16); x1 ^= x0;
    x0 += x1; x1 = rotl32(x1, 24); x1 ^= x0;
    x0 += k1; x1 += k2 + 4u;
    x0 += x1; x1 = rotl32(x1, 13); x1 ^= x0;
    x0 += x1; x1 = rotl32(x1, 15); x1 ^= x0;
    x0 += x1; x1 = rotl32(x1, 26); x1 ^= x0;
    x0 += x1; x1 = rotl32(x1,  6); x1 ^= x0;
    x0 += k2; x1 += k0 + 5u;
    o0 = x0; o1 = x1;
}

// jax_threefry_partitionable: bits(j) = a^b of threefry(key, 0, j)
__device__ inline float apply_dropout(float v, uint32_t flat, uint32_t k0, uint32_t k1) {
    uint32_t a, b;
    threefry2x32(k0, k1, 0u, flat, a, b);
    uint32_t bits = a ^ b;
    float u = __uint_as_float((bits >> 9) | 0x3F800000u) - 1.0f;
    return (u >= 0.3f) ? v * (1.0f / 0.7f) : 0.0f;
}

// ---- in-degree histogram (int) -------------------------------------------
__global__ void hist_kernel(const int* __restrict__ dst, int* __restrict__ hist) {
    int e = blockIdx.x * blockDim.x + threadIdx.x;
    if (e < N_EDGES) atomicAdd(&hist[dst[e]], 1);
}

// ---- 3-level exclusive scan over 100000 ints -----------------------------
__global__ void scan1_kernel(const int* __restrict__ hist,
                             int* __restrict__ part, int* __restrict__ bsum) {
    __shared__ int tmp[256];
    int i = blockIdx.x * 256 + threadIdx.x;
    int v = (i < N_NODES) ? hist[i] : 0;
    tmp[threadIdx.x] = v;
    __syncthreads();
    #pragma unroll
    for (int o = 1; o < 256; o <<= 1) {
        int t2 = (threadIdx.x >= o) ? tmp[threadIdx.x - o] : 0;
        __syncthreads();
        tmp[threadIdx.x] += t2;
        __syncthreads();
    }
    if (i < N_NODES) part[i] = tmp[threadIdx.x] - v;  // exclusive
    if (threadIdx.x == 255) bsum[blockIdx.x] = tmp[255];
}

__global__ void scan2_kernel(int* __restrict__ bsum, int nb) {
    __shared__ int tmp[512];
    int t = threadIdx.x;
    int v = (t < nb) ? bsum[t] : 0;
    tmp[t] = v;
    __syncthreads();
    #pragma unroll
    for (int o = 1; o < 512; o <<= 1) {
        int t2 = (t >= o) ? tmp[t - o] : 0;
        __syncthreads();
        tmp[t] += t2;
        __syncthreads();
    }
    if (t < nb) bsum[t] = tmp[t] - v;  // exclusive
}

// offsets = part + bsum[block]; cursor = offsets; dinv = rsqrt(hist+1)
__global__ void scan3_kernel(const int* __restrict__ hist,
                             const int* __restrict__ part,
                             const int* __restrict__ bsum,
                             int* __restrict__ offsets,
                             int* __restrict__ cursor,
                             float* __restrict__ dinv) {
    int i = blockIdx.x * 256 + threadIdx.x;
    if (i >= N_NODES) return;
    int o = part[i] + bsum[i >> 8];
    offsets[i] = o;
    cursor[i] = o;
    dinv[i] = rsqrtf((float)hist[i] + 1.0f);  // +1 self-loop
}

// ---- counting-sort edge positioning: sorted_src bucketed by dst ----------
__global__ void sortedge_kernel(const int* __restrict__ src,
                                const int* __restrict__ dst,
                                int* __restrict__ cursor,
                                int* __restrict__ sorted_src) {
    int e = blockIdx.x * blockDim.x + threadIdx.x;
    if (e >= N_EDGES) return;
    int pos = atomicAdd(&cursor[dst[e]], 1);
    sorted_src[pos] = src[e];
}

// ---- LayerNorm + W1 + pre-scale by dinv (one wave per node) --------------
__global__ void ln_w1_kernel(const float* __restrict__ x,
                             const float* __restrict__ gamma,
                             const float* __restrict__ beta,
                             const float* __restrict__ W1,
                             const float* __restrict__ dinv,
                             float* __restrict__ g1) {
    int wave = (blockIdx.x * blockDim.x + threadIdx.x) >> 6;
    int lane = threadIdx.x & 63;
    if (wave >= N_NODES) return;
    const float* xr = x + (size_t)wave * 128;
    float x0 = xr[lane], x1 = xr[lane + 64];

    float s = x0 + x1;
    #pragma unroll
    for (int o = 32; o; o >>= 1) s += __shfl_xor(s, o, 64);
    float mu = s * (1.0f / 128.0f);
    float d0 = x0 - mu, d1 = x1 - mu;
    float v = d0 * d0 + d1 * d1;
    #pragma unroll
    for (int o = 32; o; o >>= 1) v += __shfl_xor(v, o, 64);
    float rstd = rsqrtf(v * (1.0f / 128.0f) + 1e-5f);
    float xn0 = d0 * rstd * gamma[lane] + beta[lane];
    float xn1 = d1 * rstd * gamma[lane + 64] + beta[lane + 64];

    float p[HIDDEN];
    const float* wr0 = W1 + (size_t)lane * HIDDEN;
    const float* wr1 = W1 + (size_t)(lane + 64) * HIDDEN;
    #pragma unroll
    for (int j = 0; j < HIDDEN; j++) p[j] = xn0 * wr0[j] + xn1 * wr1[j];
    #pragma unroll
    for (int o = 32; o; o >>= 1) {
        #pragma unroll
        for (int j = 0; j < HIDDEN; j++) p[j] += __shfl_xor(p[j], o, 64);
    }
    if (lane < HIDDEN) g1[(size_t)wave * HIDDEN + lane] = p[lane] * dinv[wave];
}

// ---- pull conv1 + fused finalize1 ----------------------------------------
// One wave per node; lane = q*16 + f processes edges k = start + 4*it + q.
// acc reduced across q via shfl_xor(16,32). Epilogue: di, b1, relu,
// dropout1, @W2, *di -> g2.
__global__ void pull1_kernel(const int* __restrict__ offsets,
                             const int* __restrict__ cursor,  // = end after sort
                             const int* __restrict__ sorted_src,
                             const float* __restrict__ g1,
                             const float* __restrict__ dinv,
                             const float* __restrict__ b1,
                             const float* __restrict__ W2,
                             float* __restrict__ g2,
                             uint32_t k0, uint32_t k1) {
    __shared__ float sW2[HIDDEN * HIDDEN];
    if (threadIdx.x < HIDDEN * HIDDEN) sW2[threadIdx.x] = W2[threadIdx.x];
    __syncthreads();
    int n = blockIdx.x * 4 + (threadIdx.x >> 6);
    if (n >= N_NODES) return;
    int lane = threadIdx.x & 63;
    int q = lane >> 4, f = lane & 15;
    int start = offsets[n], end = cursor[n];

    float acc = (q == 0) ? g1[(size_t)n * HIDDEN + f] : 0.0f;  // self-loop
    for (int k = start + q; k < end; k += 4) {
        int s = sorted_src[k];
        acc += g1[(size_t)s * HIDDEN + f];
    }
    acc += __shfl_xor(acc, 16, 64);
    acc += __shfl_xor(acc, 32, 64);  // all lanes now hold full sum for f

    float di = dinv[n];
    float v = fmaxf(di * acc + b1[f], 0.0f);
    float h = apply_dropout(v, (uint32_t)(n * HIDDEN + f), k0, k1);
    // h for feature i lives in lane i (q=0 group, replicated in all q)
    float o = 0.0f;
    #pragma unroll
    for (int i = 0; i < HIDDEN; i++)
        o += __shfl(h, i, 64) * sW2[i * HIDDEN + f];
    if (q == 0) g2[(size_t)n * HIDDEN + f] = o * di;
}

// ---- pull conv2 + fused finalize2 ----------------------------------------
__global__ void pull2_kernel(const int* __restrict__ offsets,
                             const int* __restrict__ cursor,
                             const int* __restrict__ sorted_src,
                             const float* __restrict__ g2,
                             const float* __restrict__ dinv,
                             const float* __restrict__ b2,
                             float* __restrict__ out,
                             uint32_t k0, uint32_t k1) {
    int n = blockIdx.x * 4 + (threadIdx.x >> 6);
    if (n >= N_NODES) return;
    int lane = threadIdx.x & 63;
    int q = lane >> 4, f = lane & 15;
    int start = offsets[n], end = cursor[n];

    float acc = (q == 0) ? g2[(size_t)n * HIDDEN + f] : 0.0f;
    for (int k = start + q; k < end; k += 4) {
        int s = sorted_src[k];
        acc += g2[(size_t)s * HIDDEN + f];
    }
    acc += __shfl_xor(acc, 16, 64);
    acc += __shfl_xor(acc, 32, 64);

    if (q == 0) {
        float v = fmaxf(dinv[n] * acc + b2[f], 0.0f);
        out[(size_t)n * HIDDEN + f] =
            apply_dropout(v, (uint32_t)(n * HIDDEN + f), k0, k1);
    }
}

extern "C" void kernel_launch(void* const* d_in, const int* in_sizes, int n_in,
                              void* d_out, int out_size, void* d_ws, size_t ws_size,
                              hipStream_t stream) {
    const float* x     = (const float*)d_in[0];
    const int*   ei    = (const int*)d_in[1];
    const float* gamma = (const float*)d_in[2];
    const float* beta  = (const float*)d_in[3];
    const float* W1    = (const float*)d_in[4];
    const float* b1    = (const float*)d_in[5];
    const float* W2    = (const float*)d_in[6];
    const float* b2    = (const float*)d_in[7];
    float* out = (float*)d_out;
    const int* src = ei;
    const int* dst = ei + N_EDGES;

    uint32_t dk1_0, dk1_1, dk2_0, dk2_1;
    threefry2x32(0u, 42u, 0u, 0u, dk1_0, dk1_1);
    threefry2x32(0u, 42u, 0u, 1u, dk2_0, dk2_1);

    // ws layout (4B elems):
    // hist[100k] | part[100k] | bsum[512] | offsets[100k] | cursor[100k] |
    // dinv[100k] | sorted_src[6.4M] | g1[1.6M] | g2[1.6M]   (~40.4 MB)
    int*   hist       = (int*)d_ws;
    int*   part       = hist + N_NODES;
    int*   bsum       = part + N_NODES;
    int*   offsets    = bsum + 512;
    int*   cursor     = offsets + N_NODES;
    float* dinv       = (float*)(cursor + N_NODES);
    int*   sorted_src = (int*)(dinv + N_NODES);
    float* g1         = (float*)(sorted_src + N_EDGES);
    float* g2         = g1 + (size_t)N_NODES * HIDDEN;

    const int NB_N  = (N_NODES + 255) / 256;   // 391
    const int NB_E  = (N_EDGES + 255) / 256;   // 25000
    const int NB_W  = (N_NODES + 3) / 4;       // 25000 (4 waves/block)

    hipMemsetAsync(hist, 0, N_NODES * sizeof(int), stream);
    hist_kernel<<<NB_E, 256, 0, stream>>>(dst, hist);
    scan1_kernel<<<NB_N, 256, 0, stream>>>(hist, part, bsum);
    scan2_kernel<<<1, 512, 0, stream>>>(bsum, NB_N);
    scan3_kernel<<<NB_N, 256, 0, stream>>>(hist, part, bsum, offsets, cursor, dinv);
    ln_w1_kernel<<<NB_W, 256, 0, stream>>>(x, gamma, beta, W1, dinv, g1);
    sortedge_kernel<<<NB_E, 256, 0, stream>>>(src, dst, cursor, sorted_src);
    pull1_kernel<<<NB_W, 256, 0, stream>>>(offsets, cursor, sorted_src, g1,
                                           dinv, b1, W2, g2, dk1_0, dk1_1);
    pull2_kernel<<<NB_W, 256, 0, stream>>>(offsets, cursor, sorted_src, g2,
                                           dinv, b2, out, dk2_0, dk2_1);
}

// Round 4
// 908.012 us; speedup vs baseline: 1.4406x; 1.4406x over previous
//
#include <hip/hip_runtime.h>
#include <stdint.h>
#include <stddef.h>

#define N_NODES 100000
#define N_EDGES 6400000
#define HIDDEN 16
#define NBKT 782          /* ceil(100000/128) coarse buckets of 128 nodes */
#define P2CAP 14336       /* LDS sort capacity per bucket (mean 8192, sd ~90) */

__host__ __device__ inline uint32_t rotl32(uint32_t x, int n) {
    return (x << n) | (x >> (32 - n));
}

// Exact JAX threefry2x32 (20 rounds)
__host__ __device__ inline void threefry2x32(uint32_t k0, uint32_t k1,
                                             uint32_t x0, uint32_t x1,
                                             uint32_t& o0, uint32_t& o1) {
    uint32_t k2 = k0 ^ k1 ^ 0x1BD11BDAu;
    x0 += k0; x1 += k1;
    x0 += x1; x1 = rotl32(x1, 13); x1 ^= x0;
    x0 += x1; x1 = rotl32(x1, 15); x1 ^= x0;
    x0 += x1; x1 = rotl32(x1, 26); x1 ^= x0;
    x0 += x1; x1 = rotl32(x1,  6); x1 ^= x0;
    x0 += k1; x1 += k2 + 1u;
    x0 += x1; x1 = rotl32(x1, 17); x1 ^= x0;
    x0 += x1; x1 = rotl32(x1, 29); x1 ^= x0;
    x0 += x1; x1 = rotl32(x1, 16); x1 ^= x0;
    x0 += x1; x1 = rotl32(x1, 24); x1 ^= x0;
    x0 += k2; x1 += k0 + 2u;
    x0 += x1; x1 = rotl32(x1, 13); x1 ^= x0;
    x0 += x1; x1 = rotl32(x1, 15); x1 ^= x0;
    x0 += x1; x1 = rotl32(x1, 26); x1 ^= x0;
    x0 += x1; x1 = rotl32(x1,  6); x1 ^= x0;
    x0 += k0; x1 += k1 + 3u;
    x0 += x1; x1 = rotl32(x1, 17); x1 ^= x0;
    x0 += x1; x1 = rotl32(x1, 29); x1 ^= x0;
    x0 += x1; x1 = rotl32(x1, 16); x1 ^= x0;
    x0 += x1; x1 = rotl32(x1, 24); x1 ^= x0;
    x0 += k1; x1 += k2 + 4u;
    x0 += x1; x1 = rotl32(x1, 13); x1 ^= x0;
    x0 += x1; x1 = rotl32(x1, 15); x1 ^= x0;
    x0 += x1; x1 = rotl32(x1, 26); x1 ^= x0;
    x0 += x1; x1 = rotl32(x1,  6); x1 ^= x0;
    x0 += k2; x1 += k0 + 5u;
    o0 = x0; o1 = x1;
}

// jax_threefry_partitionable: bits(j) = a^b of threefry(key, 0, j)
__device__ inline float apply_dropout(float v, uint32_t flat, uint32_t k0, uint32_t k1) {
    uint32_t a, b;
    threefry2x32(k0, k1, 0u, flat, a, b);
    uint32_t bits = a ^ b;
    float u = __uint_as_float((bits >> 9) | 0x3F800000u) - 1.0f;
    return (u >= 0.3f) ? v * (1.0f / 0.7f) : 0.0f;
}

// ---- in-degree histogram (int) -------------------------------------------
__global__ void hist_kernel(const int* __restrict__ dst, int* __restrict__ hist) {
    int e = blockIdx.x * blockDim.x + threadIdx.x;
    if (e < N_EDGES) atomicAdd(&hist[dst[e]], 1);
}

// ---- 3-level exclusive scan over 100000 ints -----------------------------
__global__ void scan1_kernel(const int* __restrict__ hist,
                             int* __restrict__ part, int* __restrict__ bsum) {
    __shared__ int tmp[256];
    int i = blockIdx.x * 256 + threadIdx.x;
    int v = (i < N_NODES) ? hist[i] : 0;
    tmp[threadIdx.x] = v;
    __syncthreads();
    #pragma unroll
    for (int o = 1; o < 256; o <<= 1) {
        int t2 = (threadIdx.x >= o) ? tmp[threadIdx.x - o] : 0;
        __syncthreads();
        tmp[threadIdx.x] += t2;
        __syncthreads();
    }
    if (i < N_NODES) part[i] = tmp[threadIdx.x] - v;  // exclusive
    if (threadIdx.x == 255) bsum[blockIdx.x] = tmp[255];
}

__global__ void scan2_kernel(int* __restrict__ bsum, int nb) {
    __shared__ int tmp[512];
    int t = threadIdx.x;
    int v = (t < nb) ? bsum[t] : 0;
    tmp[t] = v;
    __syncthreads();
    #pragma unroll
    for (int o = 1; o < 512; o <<= 1) {
        int t2 = (t >= o) ? tmp[t - o] : 0;
        __syncthreads();
        tmp[t] += t2;
        __syncthreads();
    }
    if (t < nb) bsum[t] = tmp[t] - v;  // exclusive
}

// offsets = part + bsum[block]; dinv = rsqrt(hist+1)
__global__ void scan3_kernel(const int* __restrict__ hist,
                             const int* __restrict__ part,
                             const int* __restrict__ bsum,
                             int* __restrict__ offsets,
                             float* __restrict__ dinv) {
    int i = blockIdx.x * 256 + threadIdx.x;
    if (i >= N_NODES) return;
    offsets[i] = part[i] + bsum[i >> 8];
    dinv[i] = rsqrtf((float)hist[i] + 1.0f);  // +1 self-loop
}

// gcursor[b] = start of bucket b's edge range
__global__ void initcur_kernel(const int* __restrict__ offsets,
                               int* __restrict__ gcursor) {
    int b = threadIdx.x;
    if (b < NBKT) gcursor[b] = offsets[b * 128];
}

// ---- partition pass 1: bin edges into 782 coarse buckets (dst>>7) --------
// Packed word per edge: (dst&127)<<17 | src  (24 bits). LDS histogram +
// one global-cursor atomic per (block,bucket) -> writes in ~84B runs.
__global__ __launch_bounds__(256) void part1_kernel(const int* __restrict__ src,
                                                    const int* __restrict__ dst,
                                                    int* __restrict__ gcursor,
                                                    int* __restrict__ buf) {
    __shared__ int lhist[NBKT], lbase[NBKT], lcur[NBKT];
    int tid = threadIdx.x;
    size_t base = (size_t)blockIdx.x * 16384;
    for (int b = tid; b < NBKT; b += 256) { lhist[b] = 0; lcur[b] = 0; }
    __syncthreads();
    for (int i = 0; i < 64; i++) {
        size_t e = base + (size_t)i * 256 + tid;
        if (e < N_EDGES) atomicAdd(&lhist[dst[e] >> 7], 1);
    }
    __syncthreads();
    for (int b = tid; b < NBKT; b += 256) {
        int c = lhist[b];
        lbase[b] = c ? atomicAdd(&gcursor[b], c) : 0;
    }
    __syncthreads();
    for (int i = 0; i < 64; i++) {
        size_t e = base + (size_t)i * 256 + tid;
        if (e < N_EDGES) {
            int d = dst[e], s = src[e];
            int b = d >> 7;
            int pos = lbase[b] + atomicAdd(&lcur[b], 1);
            buf[pos] = ((d & 127) << 17) | s;
        }
    }
}

// ---- partition pass 2: per-bucket fine sort in LDS, in-place, coalesced --
__global__ __launch_bounds__(256) void part2_kernel(const int* __restrict__ offsets,
                                                    int* __restrict__ buf) {
    __shared__ int lcur[128];
    __shared__ int lsort[P2CAP];
    int b = blockIdx.x, tid = threadIdx.x;
    int nb = b * 128;
    int base = offsets[nb];
    int end = (b == NBKT - 1) ? N_EDGES : offsets[nb + 128];
    if (tid < 128) {
        int n = nb + tid;
        lcur[tid] = (n < N_NODES) ? (offsets[n] - base) : 0;
    }
    __syncthreads();
    int count = end - base;
    for (int i = tid; i < count; i += 256) {
        int w = buf[base + i];
        int d7 = w >> 17;
        int s = w & 0x1FFFF;
        int pos = atomicAdd(&lcur[d7], 1);
        lsort[pos] = s;
    }
    __syncthreads();
    for (int i = tid; i < count; i += 256) buf[base + i] = lsort[i];
}

// ---- LayerNorm + W1 + pre-scale by dinv (one wave per node) --------------
__global__ void ln_w1_kernel(const float* __restrict__ x,
                             const float* __restrict__ gamma,
                             const float* __restrict__ beta,
                             const float* __restrict__ W1,
                             const float* __restrict__ dinv,
                             float* __restrict__ g1) {
    int wave = (blockIdx.x * blockDim.x + threadIdx.x) >> 6;
    int lane = threadIdx.x & 63;
    if (wave >= N_NODES) return;
    const float* xr = x + (size_t)wave * 128;
    float x0 = xr[lane], x1 = xr[lane + 64];

    float s = x0 + x1;
    #pragma unroll
    for (int o = 32; o; o >>= 1) s += __shfl_xor(s, o, 64);
    float mu = s * (1.0f / 128.0f);
    float d0 = x0 - mu, d1 = x1 - mu;
    float v = d0 * d0 + d1 * d1;
    #pragma unroll
    for (int o = 32; o; o >>= 1) v += __shfl_xor(v, o, 64);
    float rstd = rsqrtf(v * (1.0f / 128.0f) + 1e-5f);
    float xn0 = d0 * rstd * gamma[lane] + beta[lane];
    float xn1 = d1 * rstd * gamma[lane + 64] + beta[lane + 64];

    float p[HIDDEN];
    const float* wr0 = W1 + (size_t)lane * HIDDEN;
    const float* wr1 = W1 + (size_t)(lane + 64) * HIDDEN;
    #pragma unroll
    for (int j = 0; j < HIDDEN; j++) p[j] = xn0 * wr0[j] + xn1 * wr1[j];
    #pragma unroll
    for (int o = 32; o; o >>= 1) {
        #pragma unroll
        for (int j = 0; j < HIDDEN; j++) p[j] += __shfl_xor(p[j], o, 64);
    }
    if (lane < HIDDEN) g1[(size_t)wave * HIDDEN + lane] = p[lane] * dinv[wave];
}

// ---- pull conv1 + fused finalize1 ----------------------------------------
// One wave per node. 64-edge batches: each lane loads one sorted_src word
// (coalesced), indices distributed via shfl; each quarter issues 16
// independent gathers (latency pipelined). Epilogue: di,b1,relu,dropout1,
// @W2, *di -> g2.
__global__ __launch_bounds__(256) void pull1_kernel(const int* __restrict__ offsets,
                             const int* __restrict__ sorted_src,
                             const float* __restrict__ g1,
                             const float* __restrict__ dinv,
                             const float* __restrict__ b1,
                             const float* __restrict__ W2,
                             float* __restrict__ g2,
                             uint32_t k0, uint32_t k1) {
    __shared__ float sW2[HIDDEN * HIDDEN];
    if (threadIdx.x < HIDDEN * HIDDEN) sW2[threadIdx.x] = W2[threadIdx.x];
    __syncthreads();
    int n = blockIdx.x * 4 + (threadIdx.x >> 6);
    if (n >= N_NODES) return;
    int lane = threadIdx.x & 63;
    int q = lane >> 4, f = lane & 15;
    int start = offsets[n];
    int end = (n == N_NODES - 1) ? N_EDGES : offsets[n + 1];

    float acc = (q == 0) ? g1[(size_t)n * HIDDEN + f] : 0.0f;  // self-loop
    for (int kb = start; kb < end; kb += 64) {
        int e = kb + lane;
        int idx = (e < end) ? sorted_src[e] : -1;
        #pragma unroll
        for (int j = 0; j < 16; j++) {
            int s = __shfl(idx, q * 16 + j, 64);
            if (s >= 0) acc += g1[(size_t)s * HIDDEN + f];
        }
    }
    acc += __shfl_xor(acc, 16, 64);
    acc += __shfl_xor(acc, 32, 64);  // all lanes hold full sum for f

    float di = dinv[n];
    float v = fmaxf(di * acc + b1[f], 0.0f);
    float h = apply_dropout(v, (uint32_t)(n * HIDDEN + f), k0, k1);
    float o = 0.0f;
    #pragma unroll
    for (int i = 0; i < HIDDEN; i++)
        o += __shfl(h, i, 64) * sW2[i * HIDDEN + f];
    if (q == 0) g2[(size_t)n * HIDDEN + f] = o * di;
}

// ---- pull conv2 + fused finalize2 ----------------------------------------
__global__ __launch_bounds__(256) void pull2_kernel(const int* __restrict__ offsets,
                             const int* __restrict__ sorted_src,
                             const float* __restrict__ g2,
                             const float* __restrict__ dinv,
                             const float* __restrict__ b2,
                             float* __restrict__ out,
                             uint32_t k0, uint32_t k1) {
    int n = blockIdx.x * 4 + (threadIdx.x >> 6);
    if (n >= N_NODES) return;
    int lane = threadIdx.x & 63;
    int q = lane >> 4, f = lane & 15;
    int start = offsets[n];
    int end = (n == N_NODES - 1) ? N_EDGES : offsets[n + 1];

    float acc = (q == 0) ? g2[(size_t)n * HIDDEN + f] : 0.0f;
    for (int kb = start; kb < end; kb += 64) {
        int e = kb + lane;
        int idx = (e < end) ? sorted_src[e] : -1;
        #pragma unroll
        for (int j = 0; j < 16; j++) {
            int s = __shfl(idx, q * 16 + j, 64);
            if (s >= 0) acc += g2[(size_t)s * HIDDEN + f];
        }
    }
    acc += __shfl_xor(acc, 16, 64);
    acc += __shfl_xor(acc, 32, 64);

    if (q == 0) {
        float v = fmaxf(dinv[n] * acc + b2[f], 0.0f);
        out[(size_t)n * HIDDEN + f] =
            apply_dropout(v, (uint32_t)(n * HIDDEN + f), k0, k1);
    }
}

extern "C" void kernel_launch(void* const* d_in, const int* in_sizes, int n_in,
                              void* d_out, int out_size, void* d_ws, size_t ws_size,
                              hipStream_t stream) {
    const float* x     = (const float*)d_in[0];
    const int*   ei    = (const int*)d_in[1];
    const float* gamma = (const float*)d_in[2];
    const float* beta  = (const float*)d_in[3];
    const float* W1    = (const float*)d_in[4];
    const float* b1    = (const float*)d_in[5];
    const float* W2    = (const float*)d_in[6];
    const float* b2    = (const float*)d_in[7];
    float* out = (float*)d_out;
    const int* src = ei;
    const int* dst = ei + N_EDGES;

    uint32_t dk1_0, dk1_1, dk2_0, dk2_1;
    threefry2x32(0u, 42u, 0u, 0u, dk1_0, dk1_1);
    threefry2x32(0u, 42u, 0u, 1u, dk2_0, dk2_1);

    // ws layout (4B elems): hist | part | bsum | offsets | dinv | gcursor |
    // buf (packed -> sorted_src, in place) | g1 | g2   (~40.0 MB)
    int*   hist    = (int*)d_ws;
    int*   part    = hist + N_NODES;
    int*   bsum    = part + N_NODES;
    int*   offsets = bsum + 512;
    float* dinv    = (float*)(offsets + N_NODES);
    int*   gcursor = (int*)(dinv + N_NODES);
    int*   buf     = gcursor + 1024;            // 6.4M words
    float* g1      = (float*)(buf + N_EDGES);
    float* g2      = g1 + (size_t)N_NODES * HIDDEN;

    const int NB_N = (N_NODES + 255) / 256;     // 391
    const int NB_E = (N_EDGES + 255) / 256;     // 25000
    const int NB_W = (N_NODES + 3) / 4;         // 25000 (4 waves/block)
    const int NB_P1 = (N_EDGES + 16383) / 16384; // 391

    hipMemsetAsync(hist, 0, N_NODES * sizeof(int), stream);
    hist_kernel<<<NB_E, 256, 0, stream>>>(dst, hist);
    scan1_kernel<<<NB_N, 256, 0, stream>>>(hist, part, bsum);
    scan2_kernel<<<1, 512, 0, stream>>>(bsum, NB_N);
    scan3_kernel<<<NB_N, 256, 0, stream>>>(hist, part, bsum, offsets, dinv);
    initcur_kernel<<<1, 1024, 0, stream>>>(offsets, gcursor);
    part1_kernel<<<NB_P1, 256, 0, stream>>>(src, dst, gcursor, buf);
    part2_kernel<<<NBKT, 256, 0, stream>>>(offsets, buf);
    ln_w1_kernel<<<NB_W, 256, 0, stream>>>(x, gamma, beta, W1, dinv, g1);
    pull1_kernel<<<NB_W, 256, 0, stream>>>(offsets, buf, g1,
                                           dinv, b1, W2, g2, dk1_0, dk1_1);
    pull2_kernel<<<NB_W, 256, 0, stream>>>(offsets, buf, g2,
                                           dinv, b2, out, dk2_0, dk2_1);
}

// Round 5
// 663.117 us; speedup vs baseline: 1.9726x; 1.3693x over previous
//
#include <hip/hip_runtime.h>
#include <stdint.h>
#include <stddef.h>

#define N_NODES 100000
#define N_EDGES 6400000
#define HIDDEN 16
#define NBKT 782          /* ceil(100000/128) coarse buckets of 128 nodes */
#define P2CAP 14336       /* LDS sort capacity per bucket (mean 8192, sd ~90) */

__host__ __device__ inline uint32_t rotl32(uint32_t x, int n) {
    return (x << n) | (x >> (32 - n));
}

// Exact JAX threefry2x32 (20 rounds)
__host__ __device__ inline void threefry2x32(uint32_t k0, uint32_t k1,
                                             uint32_t x0, uint32_t x1,
                                             uint32_t& o0, uint32_t& o1) {
    uint32_t k2 = k0 ^ k1 ^ 0x1BD11BDAu;
    x0 += k0; x1 += k1;
    x0 += x1; x1 = rotl32(x1, 13); x1 ^= x0;
    x0 += x1; x1 = rotl32(x1, 15); x1 ^= x0;
    x0 += x1; x1 = rotl32(x1, 26); x1 ^= x0;
    x0 += x1; x1 = rotl32(x1,  6); x1 ^= x0;
    x0 += k1; x1 += k2 + 1u;
    x0 += x1; x1 = rotl32(x1, 17); x1 ^= x0;
    x0 += x1; x1 = rotl32(x1, 29); x1 ^= x0;
    x0 += x1; x1 = rotl32(x1, 16); x1 ^= x0;
    x0 += x1; x1 = rotl32(x1, 24); x1 ^= x0;
    x0 += k2; x1 += k0 + 2u;
    x0 += x1; x1 = rotl32(x1, 13); x1 ^= x0;
    x0 += x1; x1 = rotl32(x1, 15); x1 ^= x0;
    x0 += x1; x1 = rotl32(x1, 26); x1 ^= x0;
    x0 += x1; x1 = rotl32(x1,  6); x1 ^= x0;
    x0 += k0; x1 += k1 + 3u;
    x0 += x1; x1 = rotl32(x1, 17); x1 ^= x0;
    x0 += x1; x1 = rotl32(x1, 29); x1 ^= x0;
    x0 += x1; x1 = rotl32(x1, 16); x1 ^= x0;
    x0 += x1; x1 = rotl32(x1, 24); x1 ^= x0;
    x0 += k1; x1 += k2 + 4u;
    x0 += x1; x1 = rotl32(x1, 13); x1 ^= x0;
    x0 += x1; x1 = rotl32(x1, 15); x1 ^= x0;
    x0 += x1; x1 = rotl32(x1, 26); x1 ^= x0;
    x0 += x1; x1 = rotl32(x1,  6); x1 ^= x0;
    x0 += k2; x1 += k0 + 5u;
    o0 = x0; o1 = x1;
}

// jax_threefry_partitionable: bits(j) = a^b of threefry(key, 0, j)
__device__ inline float apply_dropout(float v, uint32_t flat, uint32_t k0, uint32_t k1) {
    uint32_t a, b;
    threefry2x32(k0, k1, 0u, flat, a, b);
    uint32_t bits = a ^ b;
    float u = __uint_as_float((bits >> 9) | 0x3F800000u) - 1.0f;
    return (u >= 0.3f) ? v * (1.0f / 0.7f) : 0.0f;
}

// ---- coarse bucket histogram (LDS-aggregated, ~300k global atomics) ------
__global__ __launch_bounds__(256) void bhist_kernel(const int* __restrict__ dst,
                                                    int* __restrict__ bhist) {
    __shared__ int lhist[NBKT];
    int tid = threadIdx.x;
    size_t base = (size_t)blockIdx.x * 16384;
    for (int b = tid; b < NBKT; b += 256) lhist[b] = 0;
    __syncthreads();
    for (int i = 0; i < 64; i++) {
        size_t e = base + (size_t)i * 256 + tid;
        if (e < N_EDGES) atomicAdd(&lhist[dst[e] >> 7], 1);
    }
    __syncthreads();
    for (int b = tid; b < NBKT; b += 256) {
        int c = lhist[b];
        if (c) atomicAdd(&bhist[b], c);
    }
}

// ---- scan 782 bucket counts -> bko[783], gcursor -------------------------
__global__ void bscan_kernel(const int* __restrict__ bhist,
                             int* __restrict__ bko,
                             int* __restrict__ gcursor) {
    __shared__ int tmp[1024];
    int t = threadIdx.x;
    int v = (t < NBKT) ? bhist[t] : 0;
    tmp[t] = v;
    __syncthreads();
    #pragma unroll
    for (int o = 1; o < 1024; o <<= 1) {
        int t2 = (t >= o) ? tmp[t - o] : 0;
        __syncthreads();
        tmp[t] += t2;
        __syncthreads();
    }
    if (t < NBKT) {
        int excl = tmp[t] - v;
        bko[t] = excl;
        gcursor[t] = excl;
    }
    if (t == 0) bko[NBKT] = N_EDGES;
}

// ---- partition pass 1: bin edges into coarse buckets (dst>>7) ------------
// Packed word per edge: (dst&127)<<17 | src. dst cached in regs across the
// two phases (read once). Writes land in ~84B runs per (block,bucket).
__global__ __launch_bounds__(256) void part1_kernel(const int* __restrict__ src,
                                                    const int* __restrict__ dst,
                                                    int* __restrict__ gcursor,
                                                    int* __restrict__ buf) {
    __shared__ int lhist[NBKT], lbase[NBKT], lcur[NBKT];
    int tid = threadIdx.x;
    size_t base = (size_t)blockIdx.x * 16384;
    for (int b = tid; b < NBKT; b += 256) { lhist[b] = 0; lcur[b] = 0; }
    __syncthreads();
    int dv[64];
    #pragma unroll
    for (int i = 0; i < 64; i++) {
        size_t e = base + (size_t)i * 256 + tid;
        dv[i] = (e < N_EDGES) ? dst[e] : -1;
        if (dv[i] >= 0) atomicAdd(&lhist[dv[i] >> 7], 1);
    }
    __syncthreads();
    for (int b = tid; b < NBKT; b += 256) {
        int c = lhist[b];
        lbase[b] = c ? atomicAdd(&gcursor[b], c) : 0;
    }
    __syncthreads();
    #pragma unroll
    for (int i = 0; i < 64; i++) {
        size_t e = base + (size_t)i * 256 + tid;
        if (dv[i] >= 0) {
            int s = src[e];
            int b = dv[i] >> 7;
            int pos = lbase[b] + atomicAdd(&lcur[b], 1);
            buf[pos] = ((dv[i] & 127) << 17) | s;
        }
    }
}

// ---- partition pass 2: per-bucket count+scan+sort in LDS, in place -------
// Also emits offsets[n] and dinv[n] (replaces global hist + 100k scan).
__global__ __launch_bounds__(256) void part2_kernel(const int* __restrict__ bko,
                                                    int* __restrict__ buf,
                                                    int* __restrict__ offsets,
                                                    float* __restrict__ dinv) {
    __shared__ int lcnt[128], lcur[128];
    __shared__ int lsort[P2CAP];
    int b = blockIdx.x, tid = threadIdx.x;
    int base = bko[b], end = bko[b + 1];
    int count = end - base;
    if (tid < 128) lcnt[tid] = 0;
    __syncthreads();
    for (int i = tid; i < count; i += 256) {
        int w = buf[base + i];
        atomicAdd(&lcnt[w >> 17], 1);
    }
    __syncthreads();
    int v = (tid < 128) ? lcnt[tid] : 0;
    // Hillis-Steele inclusive scan over 128 counters
    #pragma unroll
    for (int o = 1; o < 128; o <<= 1) {
        int t2 = (tid < 128 && tid >= o) ? lcnt[tid - o] : 0;
        __syncthreads();
        if (tid < 128 && tid >= o) lcnt[tid] += t2;
        __syncthreads();
    }
    if (tid < 128) {
        int excl = lcnt[tid] - v;
        lcur[tid] = excl;
        int n = b * 128 + tid;
        if (n < N_NODES) {
            offsets[n] = base + excl;
            dinv[n] = rsqrtf((float)v + 1.0f);  // +1 self-loop
        }
    }
    __syncthreads();
    for (int i = tid; i < count; i += 256) {
        int w = buf[base + i];
        int pos = atomicAdd(&lcur[w >> 17], 1);
        lsort[pos] = w & 0x1FFFF;
    }
    __syncthreads();
    for (int i = tid; i < count; i += 256) buf[base + i] = lsort[i];
}

// ---- LayerNorm + W1 + pre-scale by dinv (one wave per node) --------------
__global__ void ln_w1_kernel(const float* __restrict__ x,
                             const float* __restrict__ gamma,
                             const float* __restrict__ beta,
                             const float* __restrict__ W1,
                             const float* __restrict__ dinv,
                             float* __restrict__ g1) {
    int wave = (blockIdx.x * blockDim.x + threadIdx.x) >> 6;
    int lane = threadIdx.x & 63;
    if (wave >= N_NODES) return;
    const float* xr = x + (size_t)wave * 128;
    float x0 = xr[lane], x1 = xr[lane + 64];

    float s = x0 + x1;
    #pragma unroll
    for (int o = 32; o; o >>= 1) s += __shfl_xor(s, o, 64);
    float mu = s * (1.0f / 128.0f);
    float d0 = x0 - mu, d1 = x1 - mu;
    float v = d0 * d0 + d1 * d1;
    #pragma unroll
    for (int o = 32; o; o >>= 1) v += __shfl_xor(v, o, 64);
    float rstd = rsqrtf(v * (1.0f / 128.0f) + 1e-5f);
    float xn0 = d0 * rstd * gamma[lane] + beta[lane];
    float xn1 = d1 * rstd * gamma[lane + 64] + beta[lane + 64];

    float p[HIDDEN];
    const float* wr0 = W1 + (size_t)lane * HIDDEN;
    const float* wr1 = W1 + (size_t)(lane + 64) * HIDDEN;
    #pragma unroll
    for (int j = 0; j < HIDDEN; j++) p[j] = xn0 * wr0[j] + xn1 * wr1[j];
    #pragma unroll
    for (int o = 32; o; o >>= 1) {
        #pragma unroll
        for (int j = 0; j < HIDDEN; j++) p[j] += __shfl_xor(p[j], o, 64);
    }
    if (lane < HIDDEN) g1[(size_t)wave * HIDDEN + lane] = p[lane] * dinv[wave];
}

// ---- pull conv1 + fused finalize1 ----------------------------------------
__global__ __launch_bounds__(256) void pull1_kernel(const int* __restrict__ offsets,
                             const int* __restrict__ sorted_src,
                             const float* __restrict__ g1,
                             const float* __restrict__ dinv,
                             const float* __restrict__ b1,
                             const float* __restrict__ W2,
                             float* __restrict__ g2,
                             uint32_t k0, uint32_t k1) {
    __shared__ float sW2[HIDDEN * HIDDEN];
    if (threadIdx.x < HIDDEN * HIDDEN) sW2[threadIdx.x] = W2[threadIdx.x];
    __syncthreads();
    int n = blockIdx.x * 4 + (threadIdx.x >> 6);
    if (n >= N_NODES) return;
    int lane = threadIdx.x & 63;
    int q = lane >> 4, f = lane & 15;
    int start = offsets[n];
    int end = (n == N_NODES - 1) ? N_EDGES : offsets[n + 1];

    float acc = (q == 0) ? g1[(size_t)n * HIDDEN + f] : 0.0f;  // self-loop
    for (int kb = start; kb < end; kb += 64) {
        int e = kb + lane;
        int idx = (e < end) ? sorted_src[e] : -1;
        #pragma unroll
        for (int j = 0; j < 16; j++) {
            int s = __shfl(idx, q * 16 + j, 64);
            if (s >= 0) acc += g1[(size_t)s * HIDDEN + f];
        }
    }
    acc += __shfl_xor(acc, 16, 64);
    acc += __shfl_xor(acc, 32, 64);  // all lanes hold full sum for f

    float di = dinv[n];
    float v = fmaxf(di * acc + b1[f], 0.0f);
    float h = apply_dropout(v, (uint32_t)(n * HIDDEN + f), k0, k1);
    float o = 0.0f;
    #pragma unroll
    for (int i = 0; i < HIDDEN; i++)
        o += __shfl(h, i, 64) * sW2[i * HIDDEN + f];
    if (q == 0) g2[(size_t)n * HIDDEN + f] = o * di;
}

// ---- pull conv2 + fused finalize2 ----------------------------------------
__global__ __launch_bounds__(256) void pull2_kernel(const int* __restrict__ offsets,
                             const int* __restrict__ sorted_src,
                             const float* __restrict__ g2,
                             const float* __restrict__ dinv,
                             const float* __restrict__ b2,
                             float* __restrict__ out,
                             uint32_t k0, uint32_t k1) {
    int n = blockIdx.x * 4 + (threadIdx.x >> 6);
    if (n >= N_NODES) return;
    int lane = threadIdx.x & 63;
    int q = lane >> 4, f = lane & 15;
    int start = offsets[n];
    int end = (n == N_NODES - 1) ? N_EDGES : offsets[n + 1];

    float acc = (q == 0) ? g2[(size_t)n * HIDDEN + f] : 0.0f;
    for (int kb = start; kb < end; kb += 64) {
        int e = kb + lane;
        int idx = (e < end) ? sorted_src[e] : -1;
        #pragma unroll
        for (int j = 0; j < 16; j++) {
            int s = __shfl(idx, q * 16 + j, 64);
            if (s >= 0) acc += g2[(size_t)s * HIDDEN + f];
        }
    }
    acc += __shfl_xor(acc, 16, 64);
    acc += __shfl_xor(acc, 32, 64);

    if (q == 0) {
        float v = fmaxf(dinv[n] * acc + b2[f], 0.0f);
        out[(size_t)n * HIDDEN + f] =
            apply_dropout(v, (uint32_t)(n * HIDDEN + f), k0, k1);
    }
}

extern "C" void kernel_launch(void* const* d_in, const int* in_sizes, int n_in,
                              void* d_out, int out_size, void* d_ws, size_t ws_size,
                              hipStream_t stream) {
    const float* x     = (const float*)d_in[0];
    const int*   ei    = (const int*)d_in[1];
    const float* gamma = (const float*)d_in[2];
    const float* beta  = (const float*)d_in[3];
    const float* W1    = (const float*)d_in[4];
    const float* b1    = (const float*)d_in[5];
    const float* W2    = (const float*)d_in[6];
    const float* b2    = (const float*)d_in[7];
    float* out = (float*)d_out;
    const int* src = ei;
    const int* dst = ei + N_EDGES;

    uint32_t dk1_0, dk1_1, dk2_0, dk2_1;
    threefry2x32(0u, 42u, 0u, 0u, dk1_0, dk1_1);
    threefry2x32(0u, 42u, 0u, 1u, dk2_0, dk2_1);

    // ws layout (4B elems): bhist[1024] | bko[1024] | gcursor[1024] |
    // offsets[100k] | dinv[100k] | buf[6.4M] | g1[1.6M] | g2[1.6M]
    int*   bhist   = (int*)d_ws;
    int*   bko     = bhist + 1024;
    int*   gcursor = bko + 1024;
    int*   offsets = gcursor + 1024;
    float* dinv    = (float*)(offsets + N_NODES);
    int*   buf     = (int*)(dinv + N_NODES);
    float* g1      = (float*)(buf + N_EDGES);
    float* g2      = g1 + (size_t)N_NODES * HIDDEN;

    const int NB_W  = (N_NODES + 3) / 4;          // 25000 (4 waves/block)
    const int NB_P1 = (N_EDGES + 16383) / 16384;  // 391

    hipMemsetAsync(bhist, 0, NBKT * sizeof(int), stream);
    bhist_kernel<<<NB_P1, 256, 0, stream>>>(dst, bhist);
    bscan_kernel<<<1, 1024, 0, stream>>>(bhist, bko, gcursor);
    part1_kernel<<<NB_P1, 256, 0, stream>>>(src, dst, gcursor, buf);
    part2_kernel<<<NBKT, 256, 0, stream>>>(bko, buf, offsets, dinv);
    ln_w1_kernel<<<NB_W, 256, 0, stream>>>(x, gamma, beta, W1, dinv, g1);
    pull1_kernel<<<NB_W, 256, 0, stream>>>(offsets, buf, g1,
                                           dinv, b1, W2, g2, dk1_0, dk1_1);
    pull2_kernel<<<NB_W, 256, 0, stream>>>(offsets, buf, g2,
                                           dinv, b2, out, dk2_0, dk2_1);
}